// Round 4
// baseline (167.089 us; speedup 1.0000x reference)
//
#include <hip/hip_runtime.h>

#define BB 8
#define SS 4096
#define DD 256
#define HH 1024
#define VOCAB 32000
#define NLB 500   // k_logits blocks; 4 waves each -> 2000 waves, 16 rows per wave

typedef float v2f __attribute__((ext_vector_type(2)));

__device__ __forceinline__ float wave_red_sum(float v) {
    #pragma unroll
    for (int off = 32; off; off >>= 1) v += __shfl_xor(v, off, 64);
    return v;
}

// ws layout (floats), no zero-init needed:
//   part_esum : [B][64][D] @ 0        (131072)
//   part_u    : [B][64][D] @ 131072   (131072)
//   a         : [B][D]     @ 262144   (2048)
//   vout      : [B][D]     @ 264192   (2048)
//   h         : [B][H]     @ 266240   (8192)
//   spart     : [B][NLB][2]@ 274432   (8000)   -- per-block softmax partials (m,s)

// Pass 1: part_esum[b,chunk,d] = sum over 64 tokens of (x!=0 ? emb[x,d] : 0)
__global__ __launch_bounds__(256) void k_esum(const int* __restrict__ x,
        const float* __restrict__ emb, float* __restrict__ part_esum) {
    __shared__ int toks[64];
    const int b = blockIdx.y, chunk = blockIdx.x, tid = threadIdx.x;
    if (tid < 64) toks[tid] = x[b * SS + chunk * 64 + tid];
    __syncthreads();
    float a0 = 0.f, a1 = 0.f, a2 = 0.f, a3 = 0.f;
    for (int t = 0; t < 64; t += 4) {
        int t0 = toks[t], t1 = toks[t + 1], t2 = toks[t + 2], t3 = toks[t + 3];
        if (t0) a0 += emb[t0 * DD + tid];
        if (t1) a1 += emb[t1 * DD + tid];
        if (t2) a2 += emb[t2 * DD + tid];
        if (t3) a3 += emb[t3 * DD + tid];
    }
    part_esum[(b * 64 + chunk) * DD + tid] = (a0 + a1) + (a2 + a3);
}

// esum = reduce(part_esum); qsum = wq @ esum (wave-per-row); a = wk^T @ qsum (coalesced cols)
__global__ __launch_bounds__(256) void k_qa(const float* __restrict__ part_esum,
        const float* __restrict__ wq, const float* __restrict__ wk,
        float* __restrict__ a) {
    const int b = blockIdx.x, tid = threadIdx.x, wid = tid >> 6, lane = tid & 63;
    __shared__ __align__(16) float es[DD];
    __shared__ __align__(16) float qs[DD];
    {
        float s = 0.f;
        const float* p = part_esum + b * 64 * DD + tid;
        #pragma unroll 8
        for (int c = 0; c < 64; ++c) s += p[c * DD];
        es[tid] = s;
    }
    __syncthreads();
    const float4 es4 = ((const float4*)es)[lane];
    #pragma unroll 4
    for (int r = 0; r < 64; ++r) {
        const int row = wid * 64 + r;
        const float4 w4 = ((const float4*)(wq + row * DD))[lane];
        float dp = w4.x * es4.x + w4.y * es4.y + w4.z * es4.z + w4.w * es4.w;
        dp = wave_red_sum(dp);
        if (lane == 0) qs[row] = dp;
    }
    __syncthreads();
    float a0 = 0.f, a1 = 0.f, a2 = 0.f, a3 = 0.f;
    for (int e = 0; e < DD; e += 4) {
        a0 += wk[(e + 0) * DD + tid] * qs[e + 0];
        a1 += wk[(e + 1) * DD + tid] * qs[e + 1];
        a2 += wk[(e + 2) * DD + tid] * qs[e + 2];
        a3 += wk[(e + 3) * DD + tid] * qs[e + 3];
    }
    a[b * DD + tid] = (a0 + a1) + (a2 + a3);
}

// Pass 2: part_u[b,chunk,d] = sum over 64 tokens of (a[b]·e_s) e_s[d]
__global__ __launch_bounds__(256) void k_u(const int* __restrict__ x,
        const float* __restrict__ emb, const float* __restrict__ a,
        float* __restrict__ part_u) {
    const int b = blockIdx.y, chunk = blockIdx.x, tid = threadIdx.x;
    const int wid = tid >> 6, lane = tid & 63;
    __shared__ int toks[64];
    __shared__ __align__(16) float ured[4][DD];
    if (tid < 64) toks[tid] = x[b * SS + chunk * 64 + tid];
    __syncthreads();
    const float4 a4 = ((const float4*)(a + b * DD))[lane];
    float4 up = {0.f, 0.f, 0.f, 0.f};
    for (int t = wid; t < 64; t += 4) {
        const int tok = toks[t];
        if (tok == 0) continue;
        const float4 e4 = ((const float4*)(emb + tok * DD))[lane];
        float dp = e4.x * a4.x + e4.y * a4.y + e4.z * a4.z + e4.w * a4.w;
        dp = wave_red_sum(dp);
        up.x += dp * e4.x; up.y += dp * e4.y; up.z += dp * e4.z; up.w += dp * e4.w;
    }
    ((float4*)ured[wid])[lane] = up;
    __syncthreads();
    part_u[(b * 64 + chunk) * DD + tid] =
        ured[0][tid] + ured[1][tid] + ured[2][tid] + ured[3][tid];
}

// u = reduce(part_u); vout = wv @ u (wave-per-row, coalesced)
__global__ __launch_bounds__(256) void k_vout(const float* __restrict__ part_u,
        const float* __restrict__ wv, float* __restrict__ vout) {
    const int b = blockIdx.x, tid = threadIdx.x, wid = tid >> 6, lane = tid & 63;
    __shared__ __align__(16) float us[DD];
    {
        float s = 0.f;
        const float* p = part_u + b * 64 * DD + tid;
        #pragma unroll 8
        for (int c = 0; c < 64; ++c) s += p[c * DD];
        us[tid] = s;
    }
    __syncthreads();
    const float4 u4 = ((const float4*)us)[lane];
    #pragma unroll 4
    for (int r = 0; r < 64; ++r) {
        const int row = wid * 64 + r;
        const float4 w4 = ((const float4*)(wv + row * DD))[lane];
        float dp = w4.x * u4.x + w4.y * u4.y + w4.z * u4.z + w4.w * u4.w;
        dp = wave_red_sum(dp);
        if (lane == 0) vout[b * DD + row] = dp;
    }
}

// h = relu(w1 @ vout + b1), 32 rows per block, wave-per-row
__global__ __launch_bounds__(256) void k_h(const float* __restrict__ vout,
        const float* __restrict__ w1, const float* __restrict__ b1,
        float* __restrict__ h) {
    const int b = blockIdx.y, tid = threadIdx.x, wid = tid >> 6, lane = tid & 63;
    const float4 v4 = ((const float4*)(vout + b * DD))[lane];
    const int rbase = blockIdx.x * 32 + wid * 8;
    #pragma unroll
    for (int r = 0; r < 8; ++r) {
        const int row = rbase + r;
        const float4 w4 = ((const float4*)(w1 + row * DD))[lane];
        float dp = w4.x * v4.x + w4.y * v4.y + w4.z * v4.z + w4.w * v4.w;
        dp = wave_red_sum(dp);
        if (lane == 0) h[b * HH + row] = fmaxf(dp + b1[row], 0.f);
    }
}

// logits[b,i] = h[b]·w2[i] + b2[i] -> d_out, plus fused per-block softmax partials (m,s)
__global__ __launch_bounds__(256, 2) void k_logits(const float* __restrict__ h,
        const float* __restrict__ w2, const float* __restrict__ b2,
        float* __restrict__ out, float* __restrict__ spart) {
    const int tid = threadIdx.x, wid = tid >> 6, lane = tid & 63;
    // hp[j][c*4+q] = {h[2j][k], h[2j+1][k]} at k = c*256 + lane*4 + q
    v2f hp[4][16];
    #pragma unroll
    for (int j = 0; j < 4; ++j) {
        #pragma unroll
        for (int c = 0; c < 4; ++c) {
            const float4 ta = ((const float4*)(h + (2 * j)     * HH + c * 256))[lane];
            const float4 tb = ((const float4*)(h + (2 * j + 1) * HH + c * 256))[lane];
            hp[j][c * 4 + 0] = (v2f){ta.x, tb.x};
            hp[j][c * 4 + 1] = (v2f){ta.y, tb.y};
            hp[j][c * 4 + 2] = (v2f){ta.z, tb.z};
            hp[j][c * 4 + 3] = (v2f){ta.w, tb.w};
        }
    }
    const int wg = blockIdx.x * 4 + wid;   // 0..1999
    float m_run = -1e30f, s_run = 0.f;
    #pragma unroll 2
    for (int r = 0; r < 16; ++r) {
        const int i = wg + r * 2000;
        const float4* row = (const float4*)(w2 + (size_t)i * HH);
        v2f acc[4];
        acc[0] = 0.f; acc[1] = 0.f; acc[2] = 0.f; acc[3] = 0.f;
        #pragma unroll
        for (int c = 0; c < 4; ++c) {
            const float4 w = row[c * 64 + lane];
            #define QSTEP(q, wsv) { acc[0] += hp[0][c * 4 + q] * (wsv); \
                                    acc[1] += hp[1][c * 4 + q] * (wsv); \
                                    acc[2] += hp[2][c * 4 + q] * (wsv); \
                                    acc[3] += hp[3][c * 4 + q] * (wsv); }
            QSTEP(0, w.x) QSTEP(1, w.y) QSTEP(2, w.z) QSTEP(3, w.w)
            #undef QSTEP
        }
        #pragma unroll
        for (int off = 32; off; off >>= 1) {
            #pragma unroll
            for (int j = 0; j < 4; ++j) {
                acc[j].x += __shfl_xor(acc[j].x, off, 64);
                acc[j].y += __shfl_xor(acc[j].y, off, 64);
            }
        }
        const float bias = b2[i];
        if (lane < 8) {
            float val = acc[0].x;
            val = (lane == 1) ? acc[0].y : val;
            val = (lane == 2) ? acc[1].x : val;
            val = (lane == 3) ? acc[1].y : val;
            val = (lane == 4) ? acc[2].x : val;
            val = (lane == 5) ? acc[2].y : val;
            val = (lane == 6) ? acc[3].x : val;
            val = (lane == 7) ? acc[3].y : val;
            const float lg = val + bias;
            out[lane * VOCAB + i] = lg;
            const float mn = fmaxf(m_run, lg);
            s_run = s_run * __expf(m_run - mn) + __expf(lg - mn);
            m_run = mn;
        }
    }
    __shared__ float sm[4][8], ss[4][8];
    if (lane < 8) { sm[wid][lane] = m_run; ss[wid][lane] = s_run; }
    __syncthreads();
    if (tid < 8) {
        float m = sm[0][tid], s = ss[0][tid];
        #pragma unroll
        for (int wv = 1; wv < 4; ++wv) {
            const float m2 = sm[wv][tid], s2 = ss[wv][tid];
            const float mn = fmaxf(m, m2);
            s = s * __expf(m - mn) + s2 * __expf(m2 - mn);
            m = mn;
        }
        ((v2f*)spart)[tid * NLB + blockIdx.x] = (v2f){m, s};
    }
}

// merge NLB partials per batch, then normalize the block's 1/16 slice of logits
__global__ __launch_bounds__(256) void k_norm(const float* __restrict__ spart,
        float* __restrict__ out) {
    const int b = blockIdx.y, seg = blockIdx.x, tid = threadIdx.x;
    __shared__ float rm[256], rs[256];
    const v2f* p = (const v2f*)spart + b * NLB;
    float m = -1e30f, s = 0.f;
    for (int idx = tid; idx < NLB; idx += 256) {
        const v2f t = p[idx];
        const float mn = fmaxf(m, t.x);
        s = s * __expf(m - mn) + t.y * __expf(t.x - mn);
        m = mn;
    }
    rm[tid] = m; rs[tid] = s;
    __syncthreads();
    for (int st = 128; st; st >>= 1) {
        if (tid < st) {
            const float m2 = rm[tid + st], s2 = rs[tid + st];
            const float mn = fmaxf(rm[tid], m2);
            rs[tid] = rs[tid] * __expf(rm[tid] - mn) + s2 * __expf(m2 - mn);
            rm[tid] = mn;
        }
        __syncthreads();
    }
    const float gm = rm[0], ginv = 1.f / rs[0];
    float* lg = out + b * VOCAB + seg * 2000;
    for (int i = tid; i < 2000; i += 256) lg[i] = __expf(lg[i] - gm) * ginv;
}

extern "C" void kernel_launch(void* const* d_in, const int* in_sizes, int n_in,
                              void* d_out, int out_size, void* d_ws, size_t ws_size,
                              hipStream_t stream) {
    const int*   x   = (const int*)d_in[0];
    const float* emb = (const float*)d_in[1];
    const float* wq  = (const float*)d_in[2];
    const float* wk  = (const float*)d_in[3];
    const float* wv  = (const float*)d_in[4];
    const float* w1  = (const float*)d_in[5];
    const float* b1  = (const float*)d_in[6];
    const float* w2  = (const float*)d_in[7];
    const float* b2  = (const float*)d_in[8];
    float* out = (float*)d_out;
    float* ws  = (float*)d_ws;

    float* part_esum = ws;               // 131072
    float* part_u    = ws + 131072;      // 131072
    float* a         = ws + 262144;      // 2048
    float* vout      = ws + 264192;      // 2048
    float* h         = ws + 266240;      // 8192
    float* spart     = ws + 274432;      // 8000

    k_esum<<<dim3(64, BB), 256, 0, stream>>>(x, emb, part_esum);
    k_qa<<<BB, 256, 0, stream>>>(part_esum, wq, wk, a);
    k_u<<<dim3(64, BB), 256, 0, stream>>>(x, emb, a, part_u);
    k_vout<<<BB, 256, 0, stream>>>(part_u, wv, vout);
    k_h<<<dim3(32, BB), 256, 0, stream>>>(vout, w1, b1, h);
    k_logits<<<NLB, 256, 0, stream>>>(h, w2, b2, out, spart);
    k_norm<<<dim3(16, BB), 256, 0, stream>>>(spart, out);
}

// Round 5
// 99.601 us; speedup vs baseline: 1.6776x; 1.6776x over previous
//
#include <hip/hip_runtime.h>

#define BB 8
#define SS 4096
#define DD 256
#define HH 1024
#define VOCAB 32000
#define NLB 2000   // k_logits blocks; 4 waves each; wave w owns batches 2w,2w+1; 16 rows/block

typedef float v2f __attribute__((ext_vector_type(2)));

__device__ __forceinline__ float wave_red_sum(float v) {
    #pragma unroll
    for (int off = 32; off; off >>= 1) v += __shfl_xor(v, off, 64);
    return v;
}

// ws layout (floats), no zero-init needed:
//   part_esum : [B][64][D] @ 0        (131072)
//   part_u    : [B][64][D] @ 131072   (131072)
//   a         : [B][D]     @ 262144   (2048)
//   vout      : [B][D]     @ 264192   (2048)
//   h         : [B][H]     @ 266240   (8192)
//   spart     : [B][NLB][2]@ 274432   (32000)  -- per-block softmax partials (m,s)

// Pass 1: part_esum[b,chunk,d] = sum over 64 tokens of (x!=0 ? emb[x,d] : 0)
__global__ __launch_bounds__(256) void k_esum(const int* __restrict__ x,
        const float* __restrict__ emb, float* __restrict__ part_esum) {
    __shared__ int toks[64];
    const int b = blockIdx.y, chunk = blockIdx.x, tid = threadIdx.x;
    if (tid < 64) toks[tid] = x[b * SS + chunk * 64 + tid];
    __syncthreads();
    float a0 = 0.f, a1 = 0.f, a2 = 0.f, a3 = 0.f;
    for (int t = 0; t < 64; t += 4) {
        int t0 = toks[t], t1 = toks[t + 1], t2 = toks[t + 2], t3 = toks[t + 3];
        if (t0) a0 += emb[t0 * DD + tid];
        if (t1) a1 += emb[t1 * DD + tid];
        if (t2) a2 += emb[t2 * DD + tid];
        if (t3) a3 += emb[t3 * DD + tid];
    }
    part_esum[(b * 64 + chunk) * DD + tid] = (a0 + a1) + (a2 + a3);
}

// esum = reduce(part_esum); qsum = wq @ esum (wave-per-row, 4 rows in flight); a = wk^T @ qsum
__global__ __launch_bounds__(256) void k_qa(const float* __restrict__ part_esum,
        const float* __restrict__ wq, const float* __restrict__ wk,
        float* __restrict__ a) {
    const int b = blockIdx.x, tid = threadIdx.x, wid = tid >> 6, lane = tid & 63;
    __shared__ __align__(16) float es[DD];
    __shared__ __align__(16) float qs[DD];
    {
        float s = 0.f;
        const float* p = part_esum + b * 64 * DD + tid;
        #pragma unroll 8
        for (int c = 0; c < 64; ++c) s += p[c * DD];
        es[tid] = s;
    }
    __syncthreads();
    const float4 es4 = ((const float4*)es)[lane];
    for (int r0 = 0; r0 < 64; r0 += 4) {
        float dp[4];
        #pragma unroll
        for (int j = 0; j < 4; ++j) {
            const float4 w4 = ((const float4*)(wq + (wid * 64 + r0 + j) * DD))[lane];
            dp[j] = w4.x * es4.x + w4.y * es4.y + w4.z * es4.z + w4.w * es4.w;
        }
        #pragma unroll
        for (int off = 32; off; off >>= 1) {
            #pragma unroll
            for (int j = 0; j < 4; ++j) dp[j] += __shfl_xor(dp[j], off, 64);
        }
        if (lane < 4) qs[wid * 64 + r0 + lane] = dp[lane];
    }
    __syncthreads();
    float a0 = 0.f, a1 = 0.f, a2 = 0.f, a3 = 0.f;
    for (int e = 0; e < DD; e += 4) {
        a0 += wk[(e + 0) * DD + tid] * qs[e + 0];
        a1 += wk[(e + 1) * DD + tid] * qs[e + 1];
        a2 += wk[(e + 2) * DD + tid] * qs[e + 2];
        a3 += wk[(e + 3) * DD + tid] * qs[e + 3];
    }
    a[b * DD + tid] = (a0 + a1) + (a2 + a3);
}

// Pass 2: part_u[b,chunk,d] = sum over 64 tokens of (a[b]·e_s) e_s[d]; 4 tokens in flight
__global__ __launch_bounds__(256) void k_u(const int* __restrict__ x,
        const float* __restrict__ emb, const float* __restrict__ a,
        float* __restrict__ part_u) {
    const int b = blockIdx.y, chunk = blockIdx.x, tid = threadIdx.x;
    const int wid = tid >> 6, lane = tid & 63;
    __shared__ int toks[64];
    __shared__ __align__(16) float ured[4][DD];
    if (tid < 64) toks[tid] = x[b * SS + chunk * 64 + tid];
    __syncthreads();
    const float4 a4 = ((const float4*)(a + b * DD))[lane];
    float4 up = {0.f, 0.f, 0.f, 0.f};
    for (int tt = 0; tt < 16; tt += 4) {      // wave owns tokens (tt+j)*4+wid
        int tok[4]; float4 e4[4]; float dp[4];
        #pragma unroll
        for (int j = 0; j < 4; ++j) tok[j] = toks[(tt + j) * 4 + wid];
        #pragma unroll
        for (int j = 0; j < 4; ++j) {
            e4[j] = ((const float4*)(emb + tok[j] * DD))[lane];  // tok 0 masked below
            dp[j] = e4[j].x * a4.x + e4[j].y * a4.y + e4[j].z * a4.z + e4[j].w * a4.w;
        }
        #pragma unroll
        for (int off = 32; off; off >>= 1) {
            #pragma unroll
            for (int j = 0; j < 4; ++j) dp[j] += __shfl_xor(dp[j], off, 64);
        }
        #pragma unroll
        for (int j = 0; j < 4; ++j) {
            const float m = (tok[j] != 0) ? dp[j] : 0.f;
            up.x += m * e4[j].x; up.y += m * e4[j].y;
            up.z += m * e4[j].z; up.w += m * e4[j].w;
        }
    }
    ((float4*)ured[wid])[lane] = up;
    __syncthreads();
    part_u[(b * 64 + chunk) * DD + tid] =
        ured[0][tid] + ured[1][tid] + ured[2][tid] + ured[3][tid];
}

// u = reduce(part_u); vout = wv @ u (wave-per-row, 4 rows in flight)
__global__ __launch_bounds__(256) void k_vout(const float* __restrict__ part_u,
        const float* __restrict__ wv, float* __restrict__ vout) {
    const int b = blockIdx.x, tid = threadIdx.x, wid = tid >> 6, lane = tid & 63;
    __shared__ __align__(16) float us[DD];
    {
        float s = 0.f;
        const float* p = part_u + b * 64 * DD + tid;
        #pragma unroll 8
        for (int c = 0; c < 64; ++c) s += p[c * DD];
        us[tid] = s;
    }
    __syncthreads();
    const float4 u4 = ((const float4*)us)[lane];
    for (int r0 = 0; r0 < 64; r0 += 4) {
        float dp[4];
        #pragma unroll
        for (int j = 0; j < 4; ++j) {
            const float4 w4 = ((const float4*)(wv + (wid * 64 + r0 + j) * DD))[lane];
            dp[j] = w4.x * u4.x + w4.y * u4.y + w4.z * u4.z + w4.w * u4.w;
        }
        #pragma unroll
        for (int off = 32; off; off >>= 1) {
            #pragma unroll
            for (int j = 0; j < 4; ++j) dp[j] += __shfl_xor(dp[j], off, 64);
        }
        if (lane < 4) vout[b * DD + wid * 64 + r0 + lane] = dp[lane];
    }
}

// h = relu(w1 @ vout + b1), 32 rows per block, wave-per-row (8 independent chains)
__global__ __launch_bounds__(256) void k_h(const float* __restrict__ vout,
        const float* __restrict__ w1, const float* __restrict__ b1,
        float* __restrict__ h) {
    const int b = blockIdx.y, tid = threadIdx.x, wid = tid >> 6, lane = tid & 63;
    const float4 v4 = ((const float4*)(vout + b * DD))[lane];
    const int rbase = blockIdx.x * 32 + wid * 8;
    float dp[8];
    #pragma unroll
    for (int r = 0; r < 8; ++r) {
        const float4 w4 = ((const float4*)(w1 + (rbase + r) * DD))[lane];
        dp[r] = w4.x * v4.x + w4.y * v4.y + w4.z * v4.z + w4.w * v4.w;
    }
    #pragma unroll
    for (int off = 32; off; off >>= 1) {
        #pragma unroll
        for (int r = 0; r < 8; ++r) dp[r] += __shfl_xor(dp[r], off, 64);
    }
    if (lane < 8) h[b * HH + rbase + lane] = fmaxf(dp[lane] + b1[rbase + lane], 0.f);
}

// logits: wave wid owns batches (2wid, 2wid+1); all 4 waves stream the same 16 w2 rows.
// hp = 16 v2f (32 VGPR) -> high occupancy. 6-shuffle folded reduce per row.
// Fused per-block softmax partials (m,s) per batch, no cross-wave merge needed.
__global__ __launch_bounds__(256, 4) void k_logits(const float* __restrict__ h,
        const float* __restrict__ w2, const float* __restrict__ b2,
        float* __restrict__ out, float* __restrict__ spart) {
    const int tid = threadIdx.x, wid = tid >> 6, lane = tid & 63;
    const int half = lane >> 5;               // 0 -> batch 2wid, 1 -> batch 2wid+1
    // hp[c*4+q] = {h[2wid][k], h[2wid+1][k]} at k = c*256 + lane*4 + q
    v2f hp[16];
    #pragma unroll
    for (int c = 0; c < 4; ++c) {
        const float4 ta = ((const float4*)(h + (2 * wid)     * HH + c * 256))[lane];
        const float4 tb = ((const float4*)(h + (2 * wid + 1) * HH + c * 256))[lane];
        hp[c * 4 + 0] = (v2f){ta.x, tb.x};
        hp[c * 4 + 1] = (v2f){ta.y, tb.y};
        hp[c * 4 + 2] = (v2f){ta.z, tb.z};
        hp[c * 4 + 3] = (v2f){ta.w, tb.w};
    }
    float m_run = -1e30f, s_run = 0.f;
    for (int r = 0; r < 16; ++r) {
        const int i = blockIdx.x + r * NLB;
        const float4* row = (const float4*)(w2 + (size_t)i * HH);
        v2f acc = (v2f){0.f, 0.f};
        #pragma unroll
        for (int c = 0; c < 4; ++c) {
            const float4 w = row[c * 64 + lane];
            acc += hp[c * 4 + 0] * w.x;
            acc += hp[c * 4 + 1] * w.y;
            acc += hp[c * 4 + 2] * w.z;
            acc += hp[c * 4 + 3] * w.w;
        }
        // fold across the half-wave boundary: low half keeps batch-even, high half batch-odd
        const float send = (half == 0) ? acc.y : acc.x;
        const float keep = (half == 0) ? acc.x : acc.y;
        float s = keep + __shfl_xor(send, 32, 64);
        s += __shfl_xor(s, 16, 64);
        s += __shfl_xor(s, 8, 64);
        s += __shfl_xor(s, 4, 64);
        s += __shfl_xor(s, 2, 64);
        s += __shfl_xor(s, 1, 64);
        if ((lane & 31) == 0) {
            const float lg = s + b2[i];
            out[(2 * wid + half) * VOCAB + i] = lg;
            const float mn = fmaxf(m_run, lg);
            s_run = s_run * __expf(m_run - mn) + __expf(lg - mn);
            m_run = mn;
        }
    }
    if ((lane & 31) == 0)
        ((v2f*)spart)[(2 * wid + half) * NLB + blockIdx.x] = (v2f){m_run, s_run};
}

// merge NLB partials per batch, then normalize the block's 1/16 slice of logits
__global__ __launch_bounds__(256) void k_norm(const float* __restrict__ spart,
        float* __restrict__ out) {
    const int b = blockIdx.y, seg = blockIdx.x, tid = threadIdx.x;
    __shared__ float rm[256], rs[256];
    const v2f* p = (const v2f*)spart + b * NLB;
    float m = -1e30f, s = 0.f;
    for (int idx = tid; idx < NLB; idx += 256) {
        const v2f t = p[idx];
        const float mn = fmaxf(m, t.x);
        s = s * __expf(m - mn) + t.y * __expf(t.x - mn);
        m = mn;
    }
    rm[tid] = m; rs[tid] = s;
    __syncthreads();
    for (int st = 128; st; st >>= 1) {
        if (tid < st) {
            const float m2 = rm[tid + st], s2 = rs[tid + st];
            const float mn = fmaxf(rm[tid], m2);
            rs[tid] = rs[tid] * __expf(rm[tid] - mn) + s2 * __expf(m2 - mn);
            rm[tid] = mn;
        }
        __syncthreads();
    }
    const float gm = rm[0], ginv = 1.f / rs[0];
    float* lg = out + b * VOCAB + seg * 2000;
    for (int i = tid; i < 2000; i += 256) lg[i] = __expf(lg[i] - gm) * ginv;
}

extern "C" void kernel_launch(void* const* d_in, const int* in_sizes, int n_in,
                              void* d_out, int out_size, void* d_ws, size_t ws_size,
                              hipStream_t stream) {
    const int*   x   = (const int*)d_in[0];
    const float* emb = (const float*)d_in[1];
    const float* wq  = (const float*)d_in[2];
    const float* wk  = (const float*)d_in[3];
    const float* wv  = (const float*)d_in[4];
    const float* w1  = (const float*)d_in[5];
    const float* b1  = (const float*)d_in[6];
    const float* w2  = (const float*)d_in[7];
    const float* b2  = (const float*)d_in[8];
    float* out = (float*)d_out;
    float* ws  = (float*)d_ws;

    float* part_esum = ws;               // 131072
    float* part_u    = ws + 131072;      // 131072
    float* a         = ws + 262144;      // 2048
    float* vout      = ws + 264192;      // 2048
    float* h         = ws + 266240;      // 8192
    float* spart     = ws + 274432;      // 32000

    k_esum<<<dim3(64, BB), 256, 0, stream>>>(x, emb, part_esum);
    k_qa<<<BB, 256, 0, stream>>>(part_esum, wq, wk, a);
    k_u<<<dim3(64, BB), 256, 0, stream>>>(x, emb, a, part_u);
    k_vout<<<BB, 256, 0, stream>>>(part_u, wv, vout);
    k_h<<<dim3(32, BB), 256, 0, stream>>>(vout, w1, b1, h);
    k_logits<<<NLB, 256, 0, stream>>>(h, w2, b2, out, spart);
    k_norm<<<dim3(16, BB), 256, 0, stream>>>(spart, out);
}

// Round 6
// 88.242 us; speedup vs baseline: 1.8935x; 1.1287x over previous
//
#include <hip/hip_runtime.h>

#define BB 8
#define SS 4096
#define DD 256
#define HH 1024
#define VOCAB 32000
#define NCH 128    // chunks per batch for esum/u passes (32 tokens each)
#define NLB 2000   // k_logits blocks; 4 waves each; wave w owns batches 2w,2w+1; 16 rows/block

typedef float v2f __attribute__((ext_vector_type(2)));

// ws layout (floats), no zero-init needed:
//   part_esum : [B][NCH][D] @ 0        (262144)
//   part_u    : [B][NCH][D] @ 262144   (262144)
//   a         : [B][D]      @ 524288   (2048)
//   vout      : [B][D]      @ 526336   (2048)
//   h         : [B][H]      @ 528384   (8192)
//   spart     : [B][NLB][2] @ 536576   (32000)

// Pass 1: part_esum[b,chunk,d] = sum over 32 tokens of (x!=0 ? emb[x,d] : 0)
__global__ __launch_bounds__(256) void k_esum(const int* __restrict__ x,
        const float* __restrict__ emb, float* __restrict__ part_esum) {
    __shared__ int toks[32];
    const int b = blockIdx.y, chunk = blockIdx.x, tid = threadIdx.x;
    if (tid < 32) toks[tid] = x[b * SS + chunk * 32 + tid];
    __syncthreads();
    float a0 = 0.f, a1 = 0.f, a2 = 0.f, a3 = 0.f;
    for (int t = 0; t < 32; t += 4) {
        int t0 = toks[t], t1 = toks[t + 1], t2 = toks[t + 2], t3 = toks[t + 3];
        if (t0) a0 += emb[t0 * DD + tid];
        if (t1) a1 += emb[t1 * DD + tid];
        if (t2) a2 += emb[t2 * DD + tid];
        if (t3) a3 += emb[t3 * DD + tid];
    }
    part_esum[(b * NCH + chunk) * DD + tid] = (a0 + a1) + (a2 + a3);
}

// esum = reduce(part_esum); qsum = wq @ esum (wave-per-row, 4 rows in flight); a = wk^T @ qsum
__global__ __launch_bounds__(256) void k_qa(const float* __restrict__ part_esum,
        const float* __restrict__ wq, const float* __restrict__ wk,
        float* __restrict__ a) {
    const int b = blockIdx.x, tid = threadIdx.x, wid = tid >> 6, lane = tid & 63;
    __shared__ __align__(16) float es[DD];
    __shared__ __align__(16) float qs[DD];
    {
        float s0 = 0.f, s1 = 0.f, s2 = 0.f, s3 = 0.f;
        const float* p = part_esum + b * NCH * DD + tid;
        for (int c = 0; c < NCH; c += 4) {
            s0 += p[(c + 0) * DD]; s1 += p[(c + 1) * DD];
            s2 += p[(c + 2) * DD]; s3 += p[(c + 3) * DD];
        }
        es[tid] = (s0 + s1) + (s2 + s3);
    }
    __syncthreads();
    const float4 es4 = ((const float4*)es)[lane];
    for (int r0 = 0; r0 < 64; r0 += 4) {
        float dp[4];
        #pragma unroll
        for (int j = 0; j < 4; ++j) {
            const float4 w4 = ((const float4*)(wq + (wid * 64 + r0 + j) * DD))[lane];
            dp[j] = w4.x * es4.x + w4.y * es4.y + w4.z * es4.z + w4.w * es4.w;
        }
        #pragma unroll
        for (int off = 32; off; off >>= 1) {
            #pragma unroll
            for (int j = 0; j < 4; ++j) dp[j] += __shfl_xor(dp[j], off, 64);
        }
        if (lane < 4) qs[wid * 64 + r0 + lane] = dp[lane];
    }
    __syncthreads();
    float a0 = 0.f, a1 = 0.f, a2 = 0.f, a3 = 0.f;
    for (int e = 0; e < DD; e += 4) {
        a0 += wk[(e + 0) * DD + tid] * qs[e + 0];
        a1 += wk[(e + 1) * DD + tid] * qs[e + 1];
        a2 += wk[(e + 2) * DD + tid] * qs[e + 2];
        a3 += wk[(e + 3) * DD + tid] * qs[e + 3];
    }
    a[b * DD + tid] = (a0 + a1) + (a2 + a3);
}

// Pass 2: part_u[b,chunk,d] = sum over 32 tokens of (a[b]·e_s) e_s[d]; 4 tokens in flight
__global__ __launch_bounds__(256) void k_u(const int* __restrict__ x,
        const float* __restrict__ emb, const float* __restrict__ a,
        float* __restrict__ part_u) {
    const int b = blockIdx.y, chunk = blockIdx.x, tid = threadIdx.x;
    const int wid = tid >> 6, lane = tid & 63;
    __shared__ int toks[32];
    __shared__ __align__(16) float ured[4][DD];
    if (tid < 32) toks[tid] = x[b * SS + chunk * 32 + tid];
    __syncthreads();
    const float4 a4 = ((const float4*)(a + b * DD))[lane];
    float4 up = {0.f, 0.f, 0.f, 0.f};
    #pragma unroll
    for (int tt = 0; tt < 32; tt += 16) {     // wave owns tokens tt + j*4 + wid
        int tok[4]; float4 e4[4]; float dp[4];
        #pragma unroll
        for (int j = 0; j < 4; ++j) tok[j] = toks[tt + j * 4 + wid];
        #pragma unroll
        for (int j = 0; j < 4; ++j) {
            e4[j] = ((const float4*)(emb + tok[j] * DD))[lane];  // tok 0 masked below
            dp[j] = e4[j].x * a4.x + e4[j].y * a4.y + e4[j].z * a4.z + e4[j].w * a4.w;
        }
        #pragma unroll
        for (int off = 32; off; off >>= 1) {
            #pragma unroll
            for (int j = 0; j < 4; ++j) dp[j] += __shfl_xor(dp[j], off, 64);
        }
        #pragma unroll
        for (int j = 0; j < 4; ++j) {
            const float m = (tok[j] != 0) ? dp[j] : 0.f;
            up.x += m * e4[j].x; up.y += m * e4[j].y;
            up.z += m * e4[j].z; up.w += m * e4[j].w;
        }
    }
    ((float4*)ured[wid])[lane] = up;
    __syncthreads();
    part_u[(b * NCH + chunk) * DD + tid] =
        ured[0][tid] + ured[1][tid] + ured[2][tid] + ured[3][tid];
}

// u = reduce(part_u); vout = wv @ u (wave-per-row, 4 rows in flight)
__global__ __launch_bounds__(256) void k_vout(const float* __restrict__ part_u,
        const float* __restrict__ wv, float* __restrict__ vout) {
    const int b = blockIdx.x, tid = threadIdx.x, wid = tid >> 6, lane = tid & 63;
    __shared__ __align__(16) float us[DD];
    {
        float s0 = 0.f, s1 = 0.f, s2 = 0.f, s3 = 0.f;
        const float* p = part_u + b * NCH * DD + tid;
        for (int c = 0; c < NCH; c += 4) {
            s0 += p[(c + 0) * DD]; s1 += p[(c + 1) * DD];
            s2 += p[(c + 2) * DD]; s3 += p[(c + 3) * DD];
        }
        us[tid] = (s0 + s1) + (s2 + s3);
    }
    __syncthreads();
    const float4 u4 = ((const float4*)us)[lane];
    for (int r0 = 0; r0 < 64; r0 += 4) {
        float dp[4];
        #pragma unroll
        for (int j = 0; j < 4; ++j) {
            const float4 w4 = ((const float4*)(wv + (wid * 64 + r0 + j) * DD))[lane];
            dp[j] = w4.x * u4.x + w4.y * u4.y + w4.z * u4.z + w4.w * u4.w;
        }
        #pragma unroll
        for (int off = 32; off; off >>= 1) {
            #pragma unroll
            for (int j = 0; j < 4; ++j) dp[j] += __shfl_xor(dp[j], off, 64);
        }
        if (lane < 4) vout[b * DD + wid * 64 + r0 + lane] = dp[lane];
    }
}

// h = relu(w1 @ vout + b1), 32 rows per block, wave-per-row (8 independent chains)
__global__ __launch_bounds__(256) void k_h(const float* __restrict__ vout,
        const float* __restrict__ w1, const float* __restrict__ b1,
        float* __restrict__ h) {
    const int b = blockIdx.y, tid = threadIdx.x, wid = tid >> 6, lane = tid & 63;
    const float4 v4 = ((const float4*)(vout + b * DD))[lane];
    const int rbase = blockIdx.x * 32 + wid * 8;
    float dp[8];
    #pragma unroll
    for (int r = 0; r < 8; ++r) {
        const float4 w4 = ((const float4*)(w1 + (rbase + r) * DD))[lane];
        dp[r] = w4.x * v4.x + w4.y * v4.y + w4.z * v4.z + w4.w * v4.w;
    }
    #pragma unroll
    for (int off = 32; off; off >>= 1) {
        #pragma unroll
        for (int r = 0; r < 8; ++r) dp[r] += __shfl_xor(dp[r], off, 64);
    }
    if (lane < 8) h[b * HH + rbase + lane] = fmaxf(dp[lane] + b1[rbase + lane], 0.f);
}

// logits: wave wid owns batches (2wid, 2wid+1); all 4 waves stream the same 16 w2 rows.
// unroll 2 -> two independent shuffle-reduce chains in flight.
__global__ __launch_bounds__(256, 4) void k_logits(const float* __restrict__ h,
        const float* __restrict__ w2, const float* __restrict__ b2,
        float* __restrict__ out, float* __restrict__ spart) {
    const int tid = threadIdx.x, wid = tid >> 6, lane = tid & 63;
    const int half = lane >> 5;               // 0 -> batch 2wid, 1 -> batch 2wid+1
    v2f hp[16];
    #pragma unroll
    for (int c = 0; c < 4; ++c) {
        const float4 ta = ((const float4*)(h + (2 * wid)     * HH + c * 256))[lane];
        const float4 tb = ((const float4*)(h + (2 * wid + 1) * HH + c * 256))[lane];
        hp[c * 4 + 0] = (v2f){ta.x, tb.x};
        hp[c * 4 + 1] = (v2f){ta.y, tb.y};
        hp[c * 4 + 2] = (v2f){ta.z, tb.z};
        hp[c * 4 + 3] = (v2f){ta.w, tb.w};
    }
    float m_run = -1e30f, s_run = 0.f;
    #pragma unroll 2
    for (int r = 0; r < 16; ++r) {
        const int i = blockIdx.x + r * NLB;
        const float4* row = (const float4*)(w2 + (size_t)i * HH);
        v2f acc = (v2f){0.f, 0.f};
        #pragma unroll
        for (int c = 0; c < 4; ++c) {
            const float4 w = row[c * 64 + lane];
            acc += hp[c * 4 + 0] * w.x;
            acc += hp[c * 4 + 1] * w.y;
            acc += hp[c * 4 + 2] * w.z;
            acc += hp[c * 4 + 3] * w.w;
        }
        const float send = (half == 0) ? acc.y : acc.x;
        const float keep = (half == 0) ? acc.x : acc.y;
        float s = keep + __shfl_xor(send, 32, 64);
        s += __shfl_xor(s, 16, 64);
        s += __shfl_xor(s, 8, 64);
        s += __shfl_xor(s, 4, 64);
        s += __shfl_xor(s, 2, 64);
        s += __shfl_xor(s, 1, 64);
        if ((lane & 31) == 0) {
            const float lg = s + b2[i];
            out[(2 * wid + half) * VOCAB + i] = lg;
            const float mn = fmaxf(m_run, lg);
            s_run = s_run * __expf(m_run - mn) + __expf(lg - mn);
            m_run = mn;
        }
    }
    if ((lane & 31) == 0)
        ((v2f*)spart)[(2 * wid + half) * NLB + blockIdx.x] = (v2f){m_run, s_run};
}

// merge NLB partials per batch, then normalize the block's 1/16 slice of logits
__global__ __launch_bounds__(256) void k_norm(const float* __restrict__ spart,
        float* __restrict__ out) {
    const int b = blockIdx.y, seg = blockIdx.x, tid = threadIdx.x;
    __shared__ float rm[256], rs[256];
    const v2f* p = (const v2f*)spart + b * NLB;
    float m = -1e30f, s = 0.f;
    for (int idx = tid; idx < NLB; idx += 256) {
        const v2f t = p[idx];
        const float mn = fmaxf(m, t.x);
        s = s * __expf(m - mn) + t.y * __expf(t.x - mn);
        m = mn;
    }
    rm[tid] = m; rs[tid] = s;
    __syncthreads();
    for (int st = 128; st; st >>= 1) {
        if (tid < st) {
            const float m2 = rm[tid + st], s2 = rs[tid + st];
            const float mn = fmaxf(rm[tid], m2);
            rs[tid] = rs[tid] * __expf(rm[tid] - mn) + s2 * __expf(m2 - mn);
            rm[tid] = mn;
        }
        __syncthreads();
    }
    const float gm = rm[0], ginv = 1.f / rs[0];
    float* lg = out + b * VOCAB + seg * 2000;
    for (int i = tid; i < 2000; i += 256) lg[i] = __expf(lg[i] - gm) * ginv;
}

extern "C" void kernel_launch(void* const* d_in, const int* in_sizes, int n_in,
                              void* d_out, int out_size, void* d_ws, size_t ws_size,
                              hipStream_t stream) {
    const int*   x   = (const int*)d_in[0];
    const float* emb = (const float*)d_in[1];
    const float* wq  = (const float*)d_in[2];
    const float* wk  = (const float*)d_in[3];
    const float* wv  = (const float*)d_in[4];
    const float* w1  = (const float*)d_in[5];
    const float* b1  = (const float*)d_in[6];
    const float* w2  = (const float*)d_in[7];
    const float* b2  = (const float*)d_in[8];
    float* out = (float*)d_out;
    float* ws  = (float*)d_ws;

    float* part_esum = ws;               // 262144
    float* part_u    = ws + 262144;      // 262144
    float* a         = ws + 524288;      // 2048
    float* vout      = ws + 526336;      // 2048
    float* h         = ws + 528384;      // 8192
    float* spart     = ws + 536576;      // 32000

    k_esum<<<dim3(NCH, BB), 256, 0, stream>>>(x, emb, part_esum);
    k_qa<<<BB, 256, 0, stream>>>(part_esum, wq, wk, a);
    k_u<<<dim3(NCH, BB), 256, 0, stream>>>(x, emb, a, part_u);
    k_vout<<<BB, 256, 0, stream>>>(part_u, wv, vout);
    k_h<<<dim3(32, BB), 256, 0, stream>>>(vout, w1, b1, h);
    k_logits<<<NLB, 256, 0, stream>>>(h, w2, b2, out, spart);
    k_norm<<<dim3(16, BB), 256, 0, stream>>>(spart, out);
}